// Round 5
// baseline (81.331 us; speedup 1.0000x reference)
//
#include <hip/hip_runtime.h>

// InfoNCE/contrastive MVN loss:
// loss = mean_i( LSE_j((p_i.g_j - 0.5|g_j|^2)/nv) - (p_i.g_i - 0.5|g_i|^2)/nv ) * 2nv
// B = 8192, D = 256, fp32 inputs, scalar fp32 output.
// Main kernel: bf16 MFMA GEMM (P pre-scaled by s=log2e/nv) fused with online
// base-2 LSE. G tiles staged via global_load_lds (width 16, linear LDS dest,
// inverse-XOR-swizzled global source); dual-base imm-offset ds_reads; acc
// initialized to -0.5*s*|g_j|^2 via direct LDS broadcast read.

typedef short short8 __attribute__((ext_vector_type(8)));
typedef float f32x4 __attribute__((ext_vector_type(4)));

#define LN2F 0.6931471805599453f
#define LOG2EF 1.4426950408889634f
#define NB 8192
#define ND 256
#define NCHUNK 16   // column chunks; chunk = 512 cols = 8 tiles of 64

__device__ __forceinline__ unsigned short f2bf(float f) {
  unsigned u = __float_as_uint(f);
  u += 0x7FFFu + ((u >> 16) & 1u);   // round-to-nearest-even
  return (unsigned short)(u >> 16);
}

__device__ __forceinline__ float max16(const float* z) {
  const float a = fmaxf(fmaxf(z[0], z[1]), z[2]);
  const float b = fmaxf(fmaxf(z[3], z[4]), z[5]);
  const float c = fmaxf(fmaxf(z[6], z[7]), z[8]);
  const float d = fmaxf(fmaxf(z[9], z[10]), z[11]);
  const float e = fmaxf(fmaxf(z[12], z[13]), z[14]);
  const float f = fmaxf(fmaxf(a, b), c);
  const float g = fmaxf(fmaxf(d, e), z[15]);
  return fmaxf(f, g);
}

// ---- kernel 1: convert to bf16 (P pre-scaled) + exact fp32 row stats -----
__global__ __launch_bounds__(256) void vmse_prep(
    const float* __restrict__ pred, const float* __restrict__ gt,
    const float* __restrict__ sigma,
    unsigned short* __restrict__ Ah, unsigned short* __restrict__ Bh,
    float* __restrict__ diag, float* __restrict__ gnorm,
    float* __restrict__ ghs)
{
  const float nv = sigma[0] * sigma[0];
  const float s = LOG2EF / nv;
  const int row = blockIdx.x * 4 + (threadIdx.x >> 6);
  const int lane = threadIdx.x & 63;
  const float4 p = *(const float4*)(pred + row * ND + lane * 4);
  const float4 g = *(const float4*)(gt   + row * ND + lane * 4);
  ushort4 pa, ga;
  pa.x = f2bf(p.x * s); pa.y = f2bf(p.y * s);
  pa.z = f2bf(p.z * s); pa.w = f2bf(p.w * s);
  ga.x = f2bf(g.x); ga.y = f2bf(g.y); ga.z = f2bf(g.z); ga.w = f2bf(g.w);
  *(ushort4*)(Ah + row * ND + lane * 4) = pa;
  *(ushort4*)(Bh + row * ND + lane * 4) = ga;
  float dd = p.x * g.x + p.y * g.y + p.z * g.z + p.w * g.w;
  float gg = g.x * g.x + g.y * g.y + g.z * g.z + g.w * g.w;
  #pragma unroll
  for (int off = 1; off < 64; off <<= 1) {
    dd += __shfl_xor(dd, off);
    gg += __shfl_xor(gg, off);
  }
  if (lane == 0) {
    diag[row] = dd;
    gnorm[row] = gg;
    ghs[row] = -0.5f * s * gg;   // NEGATED base-2 logit offset (acc init)
  }
}

// ---- kernel 2: fused GEMM + online base-2 LSE ----------------------------
// grid 512 = 32 row-blocks x 16 column chunks. 512 threads = 8 waves.
// Wave owns 32 pred rows (2 n-subtiles); P frags resident in VGPRs.
// G tiles (64 x 256 bf16 = 32KB) double-buffered in LDS via global_load_lds
// (linear dest, inverse-XOR-swizzled source). Reads use dual-base pointers
// (even/odd kk) + compile-time imm offsets: byte addr =
//   r15*512 + (hi^(r15&3))*16 + [rbit|1-rbit]*64 + ms*8192 + (kk&~1)*64.
// Swapped mfma(G,P): col=lane&15 -> pred, row -> gt; row-LSE lane-local.
__global__ __launch_bounds__(512, 4) void vmse_main(
    const unsigned short* __restrict__ Ah, const unsigned short* __restrict__ Bh,
    const float* __restrict__ ghs, float* __restrict__ partial)
{
  __shared__ unsigned short lds[2][64 * ND];   // 2 x 32 KB
  __shared__ float lds_ghs[512];               // chunk's (negated) offsets
  const int tid = threadIdx.x;
  const int lane = tid & 63;
  const int wid = tid >> 6;
  const int rb = blockIdx.x & 31;     // row block (256 rows)
  const int ch = blockIdx.x >> 5;     // column chunk (512 cols)
  const int r15 = lane & 15;
  const int hi = lane >> 4;
  const int j0 = ch * 512;

  // P fragments (pre-scaled): B-operand layout: n = lane&15, k = hi*8 + e
  short8 pf[2][8];
  #pragma unroll
  for (int ns = 0; ns < 2; ++ns) {
    const unsigned short* prow =
        Ah + (size_t)((rb * 256) + (wid * 32) + (ns * 16) + r15) * ND + hi * 8;
    #pragma unroll
    for (int kk = 0; kk < 8; ++kk)
      pf[ns][kk] = *(const short8*)(prow + kk * 32);
  }

  lds_ghs[tid] = ghs[j0 + tid];

  // dual-base LDS read pointers (even kk / odd kk), per buffer
  const int rbit = (r15 >> 2) & 1;
  const int h2 = hi ^ (r15 & 3);
  const char* ldsc = (const char*)&lds[0][0];
  const char* pE0 = ldsc + (r15 * 512 + h2 * 16 + rbit * 64);
  const char* pO0 = ldsc + (r15 * 512 + h2 * 16 + 64 - rbit * 64);
  const char* pE1 = pE0 + 32768;
  const char* pO1 = pO0 + 32768;

  #define STAGE(buf, t)                                                      \
    {                                                                        \
      _Pragma("unroll")                                                      \
      for (int i = 0; i < 4; ++i) {                                          \
        const int qq = wid * 4 + i;                                          \
        const int r = 2 * qq + (lane >> 5);                                  \
        const int cg = (lane & 31) ^ (r & 7);                                \
        const unsigned short* src =                                          \
            Bh + (size_t)(j0 + (t) * 64 + r) * ND + cg * 8;                  \
        __builtin_amdgcn_global_load_lds(                                    \
            (const __attribute__((address_space(1))) unsigned int*)src,      \
            (__attribute__((address_space(3))) unsigned int*)                \
                &lds[buf][qq * 512],                                         \
            16, 0, 0);                                                       \
      }                                                                      \
    }

  float m2[2], l2[2];
  #pragma unroll
  for (int ns = 0; ns < 2; ++ns) { m2[ns] = -3.0e38f; l2[ns] = 0.0f; }

  STAGE(0, 0);
  __syncthreads();   // tile 0 + lds_ghs ready

  #pragma unroll
  for (int t = 0; t < 8; ++t) {
    if (t + 1 < 8) STAGE((t + 1) & 1, t + 1);   // prefetch, stays in flight

    const char* pE = (t & 1) ? pE1 : pE0;
    const char* pO = (t & 1) ? pO1 : pO0;

    // acc init = -0.5*s*|g_j|^2 via LDS broadcast read (regs 0..3 = 4 rows)
    f32x4 acc[4][2];
    #pragma unroll
    for (int ms = 0; ms < 4; ++ms) {
      const f32x4 gv = *(const f32x4*)(&lds_ghs[t * 64 + ms * 16 + hi * 4]);
      acc[ms][0] = gv;
      acc[ms][1] = gv;
    }

    #pragma unroll
    for (int kk = 0; kk < 8; ++kk) {
      #pragma unroll
      for (int ms = 0; ms < 4; ++ms) {
        const short8 gf = (kk & 1)
            ? *(const short8*)(pO + ms * 8192 + (kk - 1) * 64)
            : *(const short8*)(pE + ms * 8192 + kk * 64);
        acc[ms][0] = __builtin_amdgcn_mfma_f32_16x16x32_bf16(gf, pf[0][kk], acc[ms][0], 0, 0, 0);
        acc[ms][1] = __builtin_amdgcn_mfma_f32_16x16x32_bf16(gf, pf[1][kk], acc[ms][1], 0, 0, 0);
      }
    }

    // single epilogue per ns over 16 base-2 logits
    #pragma unroll
    for (int ns = 0; ns < 2; ++ns) {
      float z[16];
      #pragma unroll
      for (int ms = 0; ms < 4; ++ms) {
        z[ms * 4 + 0] = acc[ms][ns][0];
        z[ms * 4 + 1] = acc[ms][ns][1];
        z[ms * 4 + 2] = acc[ms][ns][2];
        z[ms * 4 + 3] = acc[ms][ns][3];
      }
      const float tmax = max16(z);
      if (__any(tmax > m2[ns] + 8.0f)) {      // T13 defer-max, rarely taken
        const float nm = fmaxf(m2[ns], tmax);
        l2[ns] *= exp2f(m2[ns] - nm);
        m2[ns] = nm;
      }
      float e[16];
      #pragma unroll
      for (int q = 0; q < 16; ++q) e[q] = exp2f(z[q] - m2[ns]);
      float s0 = (e[0] + e[1]) + (e[2] + e[3]);
      float s1 = (e[4] + e[5]) + (e[6] + e[7]);
      float s2 = (e[8] + e[9]) + (e[10] + e[11]);
      float s3 = (e[12] + e[13]) + (e[14] + e[15]);
      l2[ns] += (s0 + s1) + (s2 + s3);
    }
    __syncthreads();   // vmcnt drain: prefetch landed; all waves done with buf
  }

  // combine lanes {i, i+16, i+32, i+48} (same pred row), write partial LSE
  #pragma unroll
  for (int ns = 0; ns < 2; ++ns) {
    float m = m2[ns], l = l2[ns];
    #pragma unroll
    for (int off = 16; off <= 32; off <<= 1) {
      const float om = __shfl_xor(m, off);
      const float ol = __shfl_xor(l, off);
      const float nm = fmaxf(m, om);
      l = l * exp2f(m - nm) + ol * exp2f(om - nm);
      m = nm;
    }
    if (hi == 0) {
      const int row = rb * 256 + wid * 32 + ns * 16 + r15;
      partial[row * NCHUNK + ch] = m + log2f(l);
    }
  }
}

// ---- kernel 3: per-row combine of chunk partials + diagonal --------------
__global__ __launch_bounds__(256) void vmse_combine(
    const float* __restrict__ partial, const float* __restrict__ diag,
    const float* __restrict__ gnorm, const float* __restrict__ sigma,
    float* __restrict__ bsum)
{
  const int r = blockIdx.x * 256 + threadIdx.x;
  const float nv = sigma[0] * sigma[0];
  float p[NCHUNK];
  float M = -3.0e38f;
  #pragma unroll
  for (int c = 0; c < NCHUNK; ++c) { p[c] = partial[r * NCHUNK + c]; M = fmaxf(M, p[c]); }
  float ssum = 0.f;
  #pragma unroll
  for (int c = 0; c < NCHUNK; ++c) ssum += exp2f(p[c] - M);
  const float lse2 = M + log2f(ssum);          // base-2 LSE of z*log2e
  const float zii = (diag[r] - 0.5f * gnorm[r]) / nv;
  float contrib = LN2F * lse2 - zii;           // lse_e - z_ii
  #pragma unroll
  for (int off = 1; off < 64; off <<= 1) contrib += __shfl_xor(contrib, off);
  __shared__ float wsum[4];
  if ((threadIdx.x & 63) == 0) wsum[threadIdx.x >> 6] = contrib;
  __syncthreads();
  if (threadIdx.x == 0)
    bsum[blockIdx.x] = (wsum[0] + wsum[1]) + (wsum[2] + wsum[3]);
}

// ---- kernel 4: deterministic finalize ------------------------------------
__global__ __launch_bounds__(64) void vmse_final(
    const float* __restrict__ bsum, const float* __restrict__ sigma,
    float* __restrict__ out)
{
  const int lane = threadIdx.x;
  float v = (lane < 32) ? bsum[lane] : 0.f;
  #pragma unroll
  for (int off = 1; off < 64; off <<= 1) v += __shfl_xor(v, off);
  if (lane == 0) {
    const float nv = sigma[0] * sigma[0];
    out[0] = v * (2.0f * nv / (float)NB);
  }
}

extern "C" void kernel_launch(void* const* d_in, const int* in_sizes, int n_in,
                              void* d_out, int out_size, void* d_ws, size_t ws_size,
                              hipStream_t stream)
{
  const float* pred  = (const float*)d_in[0];
  const float* gt    = (const float*)d_in[1];
  const float* sigma = (const float*)d_in[2];
  char* ws = (char*)d_ws;
  // ws layout: Ah 4MB | Bh 4MB | gnorm 32KB | diag 32KB | ghs 32KB | partial 512KB | bsum
  unsigned short* Ah = (unsigned short*)(ws);
  unsigned short* Bh = (unsigned short*)(ws + (4u << 20));
  float* gnorm   = (float*)(ws + (8u << 20));
  float* diag    = (float*)(ws + (8u << 20) + (32u << 10));
  float* ghs     = (float*)(ws + (8u << 20) + (64u << 10));
  float* partial = (float*)(ws + (8u << 20) + (96u << 10));
  float* bsum    = (float*)(ws + (8u << 20) + (608u << 10));

  vmse_prep<<<NB / 4, 256, 0, stream>>>(pred, gt, sigma, Ah, Bh, diag, gnorm, ghs);
  vmse_main<<<32 * NCHUNK, 512, 0, stream>>>(Ah, Bh, ghs, partial);
  vmse_combine<<<NB / 256, 256, 0, stream>>>(partial, diag, gnorm, sigma, bsum);
  vmse_final<<<1, 64, 0, stream>>>(bsum, sigma, (float*)d_out);
}

// Round 6
// 59.721 us; speedup vs baseline: 1.3619x; 1.3619x over previous
//
#include <hip/hip_runtime.h>

// InfoNCE/contrastive MVN loss:
// loss = mean_i( LSE_j((p_i.g_j - 0.5|g_j|^2)/nv) - (p_i.g_i - 0.5|g_i|^2)/nv ) * 2nv
// B = 8192, D = 256, fp32 inputs, scalar fp32 output.
// Main kernel: bf16 MFMA GEMM (P pre-scaled by s=log2e/nv) fused with online
// base-2 LSE. G tiles via global_load_lds (linear dest, inverse-XOR-swizzled
// source); dual-base imm-offset ds_reads; acc init = -0.5*s*|g|^2 via LDS
// broadcast read; raw v_exp_f32 for exp2.

typedef short short8 __attribute__((ext_vector_type(8)));
typedef float f32x4 __attribute__((ext_vector_type(4)));

#define LN2F 0.6931471805599453f
#define LOG2EF 1.4426950408889634f
#define NB 8192
#define ND 256
#define NCHUNK 16   // column chunks; chunk = 512 cols = 8 tiles of 64

#define AS1 __attribute__((address_space(1)))
#define AS3 __attribute__((address_space(3)))

__device__ __forceinline__ unsigned short f2bf(float f) {
  unsigned u = __float_as_uint(f);
  u += 0x7FFFu + ((u >> 16) & 1u);   // round-to-nearest-even
  return (unsigned short)(u >> 16);
}

__device__ __forceinline__ float fexp2(float x) {
#if __has_builtin(__builtin_amdgcn_exp2f)
  return __builtin_amdgcn_exp2f(x);   // raw v_exp_f32 (flush-to-zero under -126: fine)
#else
  float r;
  asm("v_exp_f32 %0, %1\n\ts_nop 1" : "=v"(r) : "v"(x));
  return r;
#endif
}

// ---- kernel 1: convert to bf16 (P pre-scaled) + exact fp32 row stats -----
__global__ __launch_bounds__(256) void vmse_prep(
    const float* __restrict__ pred, const float* __restrict__ gt,
    const float* __restrict__ sigma,
    unsigned short* __restrict__ Ah, unsigned short* __restrict__ Bh,
    float* __restrict__ diag, float* __restrict__ gnorm,
    float* __restrict__ ghs)
{
  const float nv = sigma[0] * sigma[0];
  const float s = LOG2EF / nv;
  const int row = blockIdx.x * 4 + (threadIdx.x >> 6);
  const int lane = threadIdx.x & 63;
  const float4 p = *(const float4*)(pred + row * ND + lane * 4);
  const float4 g = *(const float4*)(gt   + row * ND + lane * 4);
  ushort4 pa, ga;
  pa.x = f2bf(p.x * s); pa.y = f2bf(p.y * s);
  pa.z = f2bf(p.z * s); pa.w = f2bf(p.w * s);
  ga.x = f2bf(g.x); ga.y = f2bf(g.y); ga.z = f2bf(g.z); ga.w = f2bf(g.w);
  *(ushort4*)(Ah + row * ND + lane * 4) = pa;
  *(ushort4*)(Bh + row * ND + lane * 4) = ga;
  float dd = p.x * g.x + p.y * g.y + p.z * g.z + p.w * g.w;
  float gg = g.x * g.x + g.y * g.y + g.z * g.z + g.w * g.w;
  #pragma unroll
  for (int off = 1; off < 64; off <<= 1) {
    dd += __shfl_xor(dd, off);
    gg += __shfl_xor(gg, off);
  }
  if (lane == 0) {
    diag[row] = dd;
    gnorm[row] = gg;
    ghs[row] = -0.5f * s * gg;   // NEGATED base-2 logit offset (acc init)
  }
}

// per-4-logit online LSE epilogue
__device__ __forceinline__ void epi(const f32x4 z, float& m, float& l) {
  const float tmax = fmaxf(fmaxf(z[0], z[1]), fmaxf(z[2], z[3]));
  if (__any(tmax > m + 8.0f)) {      // T13 defer-max, rarely taken
    const float nm = fmaxf(m, tmax);
    l *= fexp2(m - nm);
    m = nm;
  }
  l += (fexp2(z[0] - m) + fexp2(z[1] - m)) + (fexp2(z[2] - m) + fexp2(z[3] - m));
}

// ---- kernel 2: fused GEMM + online base-2 LSE ----------------------------
// grid 512 = 32 row-blocks x 16 column chunks. 512 threads = 8 waves.
// Wave owns 32 pred rows (2 n-subtiles); P frags resident in VGPRs.
// G tiles (64 x 256 bf16 = 32KB) double-buffered in LDS via global_load_lds
// (linear dest, inverse-XOR-swizzled source). ds_reads use dual base pointers
// (even/odd kk) + compile-time imm offsets: byte addr =
//   r15*512 + (hi^(r15&3))*16 + [rbit | 1-rbit]*64 + ms*8192 + (kk&~1)*64.
// Swapped mfma(G,P): col=lane&15 -> pred, row -> gt; row-LSE lane-local.
__global__ __launch_bounds__(512, 4) void vmse_main(
    const unsigned short* __restrict__ Ah, const unsigned short* __restrict__ Bh,
    const float* __restrict__ ghs, float* __restrict__ partial)
{
  __shared__ unsigned short lds[2][64 * ND];   // 2 x 32 KB
  __shared__ float lds_ghs[512];               // chunk's (negated) offsets
  const int tid = threadIdx.x;
  const int lane = tid & 63;
  const int wid = tid >> 6;
  const int rb = blockIdx.x & 31;     // row block (256 rows)
  const int ch = blockIdx.x >> 5;     // column chunk (512 cols)
  const int r15 = lane & 15;
  const int hi = lane >> 4;
  const int j0 = ch * 512;

  // P fragments (pre-scaled): B-operand layout: n = lane&15, k = hi*8 + e
  short8 pf[2][8];
  #pragma unroll
  for (int ns = 0; ns < 2; ++ns) {
    const unsigned short* prow =
        Ah + (size_t)((rb * 256) + (wid * 32) + (ns * 16) + r15) * ND + hi * 8;
    #pragma unroll
    for (int kk = 0; kk < 8; ++kk)
      pf[ns][kk] = *(const short8*)(prow + kk * 32);
  }

  lds_ghs[tid] = ghs[j0 + tid];

  // dual-base LDS read pointers (even kk / odd kk), per buffer
  const int rbit = (r15 >> 2) & 1;
  const int h2 = hi ^ (r15 & 3);
  const char* ldsc = (const char*)&lds[0][0];
  const char* pE0 = ldsc + (r15 * 512 + h2 * 16 + rbit * 64);
  const char* pO0 = ldsc + (r15 * 512 + h2 * 16 + 64 - rbit * 64);
  const char* pE1 = pE0 + 32768;
  const char* pO1 = pO0 + 32768;

  // per-lane staging source pointers (t=0); +t*16384 ushorts per tile
  const unsigned short* srcb[4];
  #pragma unroll
  for (int i = 0; i < 4; ++i) {
    const int qq = wid * 4 + i;
    const int r = 2 * qq + (lane >> 5);
    const int cg = (lane & 31) ^ (r & 7);
    srcb[i] = Bh + (size_t)(j0 + r) * ND + cg * 8;
  }

  #define STAGE(buf, t)                                                      \
    {                                                                        \
      _Pragma("unroll")                                                      \
      for (int i = 0; i < 4; ++i)                                            \
        __builtin_amdgcn_global_load_lds(                                    \
            (const AS1 unsigned int*)(srcb[i] + (t) * 16384),                \
            (AS3 unsigned int*)&lds[buf][(wid * 4 + i) * 512], 16, 0, 0);    \
    }

  float m2[2], l2[2];
  #pragma unroll
  for (int ns = 0; ns < 2; ++ns) { m2[ns] = -3.0e38f; l2[ns] = 0.0f; }

  // one 64-col tile: 4 ms-subtiles of {acc init from LDS, 16 MFMA, epilogue}
  #define COMPUTE(pE, pO, gp)                                                \
    {                                                                        \
      _Pragma("unroll")                                                      \
      for (int ms = 0; ms < 4; ++ms) {                                       \
        const char* gpm = (gp) + ms * 64 + hi * 16;                          \
        f32x4 a0 = *(const f32x4*)gpm;                                       \
        f32x4 a1 = a0;                                                       \
        _Pragma("unroll")                                                    \
        for (int kk = 0; kk < 8; ++kk) {                                     \
          const short8 gf = (kk & 1)                                         \
              ? *(const short8*)((pO) + ms * 8192 + (kk - 1) * 64)           \
              : *(const short8*)((pE) + ms * 8192 + kk * 64);                \
          a0 = __builtin_amdgcn_mfma_f32_16x16x32_bf16(gf, pf[0][kk], a0, 0, 0, 0); \
          a1 = __builtin_amdgcn_mfma_f32_16x16x32_bf16(gf, pf[1][kk], a1, 0, 0, 0); \
        }                                                                    \
        epi(a0, m2[0], l2[0]);                                               \
        epi(a1, m2[1], l2[1]);                                               \
      }                                                                      \
    }

  STAGE(0, 0);
  __syncthreads();   // tile 0 + lds_ghs ready

  const char* gp = (const char*)lds_ghs;
  for (int tt = 0; tt < 4; ++tt) {
    const int t = 2 * tt;
    STAGE(1, t + 1);                   // prefetch, stays in flight
    COMPUTE(pE0, pO0, gp);
    gp += 256;
    __syncthreads();                   // prefetch landed; buf0 free
    if (t + 2 < 8) STAGE(0, t + 2);
    COMPUTE(pE1, pO1, gp);
    gp += 256;
    __syncthreads();                   // prefetch landed; buf1 free
  }

  // combine lanes {i, i+16, i+32, i+48} (same pred row), write partial LSE
  #pragma unroll
  for (int ns = 0; ns < 2; ++ns) {
    float m = m2[ns], l = l2[ns];
    #pragma unroll
    for (int off = 16; off <= 32; off <<= 1) {
      const float om = __shfl_xor(m, off);
      const float ol = __shfl_xor(l, off);
      const float nm = fmaxf(m, om);
      l = l * fexp2(m - nm) + ol * fexp2(om - nm);
      m = nm;
    }
    if (hi == 0) {
      const int row = rb * 256 + wid * 32 + ns * 16 + r15;
      partial[row * NCHUNK + ch] = m + log2f(l);
    }
  }
}

// ---- kernel 3: per-row combine of chunk partials + diagonal --------------
__global__ __launch_bounds__(256) void vmse_combine(
    const float* __restrict__ partial, const float* __restrict__ diag,
    const float* __restrict__ gnorm, const float* __restrict__ sigma,
    float* __restrict__ bsum)
{
  const int r = blockIdx.x * 256 + threadIdx.x;
  const float nv = sigma[0] * sigma[0];
  float p[NCHUNK];
  float M = -3.0e38f;
  #pragma unroll
  for (int c = 0; c < NCHUNK; ++c) { p[c] = partial[r * NCHUNK + c]; M = fmaxf(M, p[c]); }
  float ssum = 0.f;
  #pragma unroll
  for (int c = 0; c < NCHUNK; ++c) ssum += exp2f(p[c] - M);
  const float lse2 = M + log2f(ssum);          // base-2 LSE of z*log2e
  const float zii = (diag[r] - 0.5f * gnorm[r]) / nv;
  float contrib = LN2F * lse2 - zii;           // lse_e - z_ii
  #pragma unroll
  for (int off = 1; off < 64; off <<= 1) contrib += __shfl_xor(contrib, off);
  __shared__ float wsum[4];
  if ((threadIdx.x & 63) == 0) wsum[threadIdx.x >> 6] = contrib;
  __syncthreads();
  if (threadIdx.x == 0)
    bsum[blockIdx.x] = (wsum[0] + wsum[1]) + (wsum[2] + wsum[3]);
}

// ---- kernel 4: deterministic finalize ------------------------------------
__global__ __launch_bounds__(64) void vmse_final(
    const float* __restrict__ bsum, const float* __restrict__ sigma,
    float* __restrict__ out)
{
  const int lane = threadIdx.x;
  float v = (lane < 32) ? bsum[lane] : 0.f;
  #pragma unroll
  for (int off = 1; off < 64; off <<= 1) v += __shfl_xor(v, off);
  if (lane == 0) {
    const float nv = sigma[0] * sigma[0];
    out[0] = v * (2.0f * nv / (float)NB);
  }
}

extern "C" void kernel_launch(void* const* d_in, const int* in_sizes, int n_in,
                              void* d_out, int out_size, void* d_ws, size_t ws_size,
                              hipStream_t stream)
{
  const float* pred  = (const float*)d_in[0];
  const float* gt    = (const float*)d_in[1];
  const float* sigma = (const float*)d_in[2];
  char* ws = (char*)d_ws;
  // ws layout: Ah 4MB | Bh 4MB | gnorm 32KB | diag 32KB | ghs 32KB | partial 512KB | bsum
  unsigned short* Ah = (unsigned short*)(ws);
  unsigned short* Bh = (unsigned short*)(ws + (4u << 20));
  float* gnorm   = (float*)(ws + (8u << 20));
  float* diag    = (float*)(ws + (8u << 20) + (32u << 10));
  float* ghs     = (float*)(ws + (8u << 20) + (64u << 10));
  float* partial = (float*)(ws + (8u << 20) + (96u << 10));
  float* bsum    = (float*)(ws + (8u << 20) + (608u << 10));

  vmse_prep<<<NB / 4, 256, 0, stream>>>(pred, gt, sigma, Ah, Bh, diag, gnorm, ghs);
  vmse_main<<<32 * NCHUNK, 512, 0, stream>>>(Ah, Bh, ghs, partial);
  vmse_combine<<<NB / 256, 256, 0, stream>>>(partial, diag, gnorm, sigma, bsum);
  vmse_final<<<1, 64, 0, stream>>>(bsum, sigma, (float*)d_out);
}